// Round 1
// baseline (492.841 us; speedup 1.0000x reference)
//
#include <hip/hip_runtime.h>
#include <cstdint>
#include <cstddef>

#define CC   96
#define BB   32
#define HHn  112
#define WWn  112
#define HWn  (HHn*WWn)        // 12544
#define NPIX (BB*HWn)         // 401408
#define EPSf 1e-5f

// ---------------- w_mix transpose: wT[c*96+o] = w[o*96+c] ----------------
__global__ __launch_bounds__(256) void k_transpose(const float* __restrict__ w,
                                                   float* __restrict__ wT) {
  int i = blockIdx.x * 256 + threadIdx.x;
  if (i < CC * CC) {
    int o = i / CC, c = i % CC;
    wT[c * CC + o] = w[i];
  }
}

// ---------------- depthwise 7x7 conv, 4 pixels per thread ----------------
__global__ __launch_bounds__(256) void k_conv(const float* __restrict__ x,
                                              const float* __restrict__ hk,
                                              float* __restrict__ feat) {
  long t = (long)blockIdx.x * 256 + threadIdx.x;   // B*C*HW/4 threads
  int pw = ((int)(t % 28)) * 4;                    // w0 of the 4-pixel group
  long rest = t / 28;                              // (b*C+c)*H + h
  int h = (int)(rest % HHn);
  long bc = rest / HHn;                            // b*C + c
  int c = (int)(bc % CC);
  const float* xc = x + bc * (long)HWn;
  const float* kc = hk + c * 49;

  float a0 = 0.f, a1 = 0.f, a2 = 0.f, a3 = 0.f;
  // load window covers pw-4 .. pw+7 via 3 float4s; clamp addresses at edges,
  // zero the out-of-range r[] entries branchlessly.
  const bool leftEdge  = (pw == 0);
  const bool rightEdge = (pw == WWn - 4);          // pw == 108
  int offA = leftEdge ? 0 : pw - 4;
  int offC = rightEdge ? WWn - 4 : pw + 4;

#pragma unroll
  for (int kh = 0; kh < 7; ++kh) {
    int hh = h + kh - 3;
    if ((unsigned)hh < (unsigned)HHn) {
      const float* row = xc + hh * WWn;
      float4 va = *(const float4*)(row + offA);
      float4 vb = *(const float4*)(row + pw);
      float4 vc = *(const float4*)(row + offC);
      float r[10];
      r[0] = leftEdge ? 0.f : va.y;
      r[1] = leftEdge ? 0.f : va.z;
      r[2] = leftEdge ? 0.f : va.w;
      r[3] = vb.x; r[4] = vb.y; r[5] = vb.z; r[6] = vb.w;
      r[7] = rightEdge ? 0.f : vc.x;
      r[8] = rightEdge ? 0.f : vc.y;
      r[9] = rightEdge ? 0.f : vc.z;
#pragma unroll
      for (int kw = 0; kw < 7; ++kw) {
        float kv = kc[kh * 7 + kw];
        a0 = fmaf(r[kw],     kv, a0);
        a1 = fmaf(r[kw + 1], kv, a1);
        a2 = fmaf(r[kw + 2], kv, a2);
        a3 = fmaf(r[kw + 3], kv, a3);
      }
    }
  }
  float4 o4; o4.x = a0; o4.y = a1; o4.z = a2; o4.w = a3;
  *(float4*)(feat + t * 4) = o4;
}

// ---------------- 1x1 mix: mixed[b,o,p] = sum_c feat[b,c,p]*w[o,c] + bias[o]
__global__ __launch_bounds__(256) void k_mix(const float* __restrict__ feat,
                                             const float* __restrict__ wT,
                                             const float* __restrict__ bmix,
                                             float* __restrict__ mixed) {
  int tid = threadIdx.x;
  int bid = blockIdx.x;                // b*49 + tile
  int b = bid / 49;
  int p = (bid % 49) * 256 + tid;      // pixel within image
  const float* fb = feat + (long)b * CC * HWn + p;

  float acc[CC];
#pragma unroll
  for (int o = 0; o < CC; ++o) acc[o] = 0.f;

  for (int c = 0; c < CC; ++c) {
    float f = fb[(long)c * HWn];
    const float* wc = wT + c * CC;     // wave-uniform -> scalar loads
#pragma unroll
    for (int o = 0; o < CC; ++o) acc[o] = fmaf(f, wc[o], acc[o]);
  }

  float* mb = mixed + (long)b * CC * HWn + p;
#pragma unroll
  for (int o = 0; o < CC; ++o) mb[(long)o * HWn] = acc[o] + bmix[o];
}

// ---------------- per-channel sum / sumsq over (b,h,w) ----------------
__global__ __launch_bounds__(256) void k_stats(const float* __restrict__ mixed,
                                               float* __restrict__ ssum,
                                               float* __restrict__ ssq) {
  int b = blockIdx.x;   // 32
  int o = blockIdx.y;   // 96
  const float4* p4 = (const float4*)(mixed + ((long)b * CC + o) * HWn);
  float s = 0.f, q = 0.f;
  for (int i = threadIdx.x; i < HWn / 4; i += 256) {
    float4 v = p4[i];
    s += v.x + v.y + v.z + v.w;
    q += v.x * v.x + v.y * v.y + v.z * v.z + v.w * v.w;
  }
  __shared__ float ls[256], lq[256];
  ls[threadIdx.x] = s; lq[threadIdx.x] = q;
  __syncthreads();
  for (int st = 128; st > 0; st >>= 1) {
    if (threadIdx.x < st) {
      ls[threadIdx.x] += ls[threadIdx.x + st];
      lq[threadIdx.x] += lq[threadIdx.x + st];
    }
    __syncthreads();
  }
  if (threadIdx.x == 0) {
    atomicAdd(&ssum[o], ls[0]);
    atomicAdd(&ssq[o], lq[0]);
  }
}

__global__ void k_finalize(const float* __restrict__ ssum,
                           const float* __restrict__ ssq,
                           float* __restrict__ meanv,
                           float* __restrict__ rstdv) {
  int o = threadIdx.x;
  if (o < CC) {
    float m = ssum[o] * (1.0f / NPIX);
    float v = ssq[o] * (1.0f / NPIX) - m * m;
    meanv[o] = m;
    rstdv[o] = 1.0f / sqrtf(v + EPSf);
  }
}

// ---------------- BN (affine=False) + exact GELU ----------------
__global__ __launch_bounds__(256) void k_bngelu(const float* __restrict__ mixed,
                                                const float* __restrict__ meanv,
                                                const float* __restrict__ rstdv,
                                                float* __restrict__ out) {
  long i4 = (long)blockIdx.x * 256 + threadIdx.x;
  long e = i4 * 4;
  int o = (int)((e / HWn) % CC);       // all 4 elems in same channel plane
  float m = meanv[o], r = rstdv[o];
  float4 v = *(const float4*)(mixed + e);
  float4 g;
  float z;
  z = (v.x - m) * r; g.x = 0.5f * z * (1.0f + erff(z * 0.70710678118654752f));
  z = (v.y - m) * r; g.y = 0.5f * z * (1.0f + erff(z * 0.70710678118654752f));
  z = (v.z - m) * r; g.z = 0.5f * z * (1.0f + erff(z * 0.70710678118654752f));
  z = (v.w - m) * r; g.w = 0.5f * z * (1.0f + erff(z * 0.70710678118654752f));
  *(float4*)(out + e) = g;
}

extern "C" void kernel_launch(void* const* d_in, const int* in_sizes, int n_in,
                              void* d_out, int out_size, void* d_ws, size_t ws_size,
                              hipStream_t stream) {
  const float* hk   = (const float*)d_in[0];   // local_hk [96,1,7,7]
  const float* x    = (const float*)d_in[1];   // x [32,96,112,112]
  const float* wmix = (const float*)d_in[2];   // w_mix [96,96]
  const float* bmix = (const float*)d_in[3];   // b_mix [96]
  float* out = (float*)d_out;

  char* ws = (char*)d_ws;
  float* stats = (float*)ws;                   // sum[96], ssq[96], mean[96], rstd[96]
  float* wT    = (float*)(ws + 2048);          // 96*96 floats
  float* mixed = (float*)(ws + 40960);         // 38,535,168 floats (154 MB)
  float* feat  = out;                          // reuse d_out as conv scratch

  hipMemsetAsync(stats, 0, 768, stream);       // zero sum+ssq each call

  k_transpose<<<36, 256, 0, stream>>>(wmix, wT);
  k_conv<<<37632, 256, 0, stream>>>(x, hk, feat);
  k_mix<<<1568, 256, 0, stream>>>(feat, wT, bmix, mixed);
  k_stats<<<dim3(32, 96), 256, 0, stream>>>(mixed, stats, stats + 96);
  k_finalize<<<1, 128, 0, stream>>>(stats, stats + 96, stats + 192, stats + 288);
  k_bngelu<<<37632, 256, 0, stream>>>(mixed, stats + 192, stats + 288, out);
}